// Round 1
// baseline (131.254 us; speedup 1.0000x reference)
//
#include <hip/hip_runtime.h>

#define NPTS 4096
#define BLK  128
#define CHUNKS (NPTS / BLK)   // 32 chunks per (dir, batch)

// Grid: 2 dirs * 8 batches * 32 chunks = 512 blocks of 128 threads.
// dir 0: threads own x points, LDS holds y  -> min over j (axis=2 term)
// dir 1: threads own y points, LDS holds x  -> min over i (axis=1 term)
__global__ __launch_bounds__(BLK) void chamfer_kernel(
    const float* __restrict__ x,
    const float* __restrict__ y,
    float* __restrict__ out)
{
    __shared__ float4 sB[NPTS];   // 64 KB: (p0, p1, p2, |p|^2)

    const int bid   = blockIdx.x;
    const int dir   = bid >> 8;        // 0..1
    const int rem   = bid & 255;
    const int b     = rem >> 5;        // 0..7
    const int chunk = rem & 31;        // 0..31
    const int tid   = threadIdx.x;

    const float* __restrict__ A  = dir ? y : x;
    const float* __restrict__ Bm = dir ? x : y;
    const float* __restrict__ Ab = A  + (size_t)b * (NPTS * 3);
    const float* __restrict__ Bb = Bm + (size_t)b * (NPTS * 3);

    // ---- stage opposing cloud into LDS with norms ----
    for (int k = tid; k < NPTS; k += BLK) {
        float b0 = Bb[3 * k + 0];
        float b1 = Bb[3 * k + 1];
        float b2 = Bb[3 * k + 2];
        sB[k] = make_float4(b0, b1, b2, b0 * b0 + b1 * b1 + b2 * b2);
    }

    // ---- own point ----
    const int p = chunk * BLK + tid;
    const float a0 = Ab[3 * p + 0];
    const float a1 = Ab[3 * p + 1];
    const float a2 = Ab[3 * p + 2];
    const float an = a0 * a0 + a1 * a1 + a2 * a2;

    __syncthreads();

    // ---- main loop: min over all 4096 LDS points ----
    // 4 independent accumulators to break the v_min dependency chain.
    float m0 = 1e30f, m1 = 1e30f, m2 = 1e30f, m3 = 1e30f;
    for (int j = 0; j < NPTS; j += 4) {
        float4 q0 = sB[j + 0];
        float4 q1 = sB[j + 1];
        float4 q2 = sB[j + 2];
        float4 q3 = sB[j + 3];
        // d = (an + bn) - 2*dot  (same expansion as the reference)
        float d0 = fmaf(-2.f, fmaf(a0, q0.x, fmaf(a1, q0.y, a2 * q0.z)), an + q0.w);
        float d1 = fmaf(-2.f, fmaf(a0, q1.x, fmaf(a1, q1.y, a2 * q1.z)), an + q1.w);
        float d2 = fmaf(-2.f, fmaf(a0, q2.x, fmaf(a1, q2.y, a2 * q2.z)), an + q2.w);
        float d3 = fmaf(-2.f, fmaf(a0, q3.x, fmaf(a1, q3.y, a2 * q3.z)), an + q3.w);
        m0 = fminf(m0, d0);
        m1 = fminf(m1, d1);
        m2 = fminf(m2, d2);
        m3 = fminf(m3, d3);
    }
    float mv = fminf(fminf(m0, m1), fminf(m2, m3));

    // ---- block reduction: sum of per-thread mins ----
    #pragma unroll
    for (int off = 32; off > 0; off >>= 1)
        mv += __shfl_down(mv, off);   // width = wave = 64

    const int lane = tid & 63;
    const int wave = tid >> 6;        // 0..1

    __syncthreads();                  // everyone done reading sB; reuse it
    float* red = (float*)sB;
    if (lane == 0) red[wave] = mv;
    __syncthreads();

    if (tid == 0) {
        float s = red[0] + red[1];
        // each direction's mean divides by 8*4096; loss scale 0.005
        atomicAdd(out, s * (0.005f / 32768.f));
    }
}

extern "C" void kernel_launch(void* const* d_in, const int* in_sizes, int n_in,
                              void* d_out, int out_size, void* d_ws, size_t ws_size,
                              hipStream_t stream) {
    const float* x = (const float*)d_in[0];
    const float* y = (const float*)d_in[1];
    float* out = (float*)d_out;

    // output is re-poisoned to 0xAA before every timed launch — zero it
    hipMemsetAsync(out, 0, sizeof(float), stream);

    dim3 grid(2 * 8 * CHUNKS);   // 512
    dim3 block(BLK);             // 128
    chamfer_kernel<<<grid, block, 0, stream>>>(x, y, out);
}

// Round 2
// 106.232 us; speedup vs baseline: 1.2355x; 1.2355x over previous
//
#include <hip/hip_runtime.h>

#define NPTS   4096
#define NB     8
#define THR    256
#define AOWN   2                    // A points per thread
#define APB    (THR * AOWN)         // 512 A pts per block
#define ACH    (NPTS / APB)         // 8 A chunks
#define BCH    8                    // B chunks
#define BCHPTS (NPTS / BCH)         // 512 pts per B chunk

// ---------------- pass 0: pack (p0,p1,p2,|p|^2) ----------------
// packed[0      .. 32767] = x (8 batches * 4096)
// packed[32768 .. 65535] = y
__global__ __launch_bounds__(256) void prep_kernel(
    const float* __restrict__ x, const float* __restrict__ y,
    float4* __restrict__ packed)
{
    int i = blockIdx.x * 256 + threadIdx.x;          // 0..65535
    const float* src = (i < NB * NPTS) ? x : y;
    int j = (i < NB * NPTS) ? i : i - NB * NPTS;
    float p0 = src[3 * j + 0];
    float p1 = src[3 * j + 1];
    float p2 = src[3 * j + 2];
    packed[i] = make_float4(p0, p1, p2, p0 * p0 + p1 * p1 + p2 * p2);
}

// ---------------- pass 1: partial mins ----------------
// grid = 2 dirs * 8 batches * 8 A-chunks * 8 B-chunks = 1024 blocks
__global__ __launch_bounds__(THR, 4) void chamfer_main(
    const float4* __restrict__ packed,
    int* __restrict__ mins)
{
    const int bid = blockIdx.x;
    const int bCh = bid & 7;
    const int aCh = (bid >> 3) & 7;
    const int db  = bid >> 6;            // dir*8 + batch, 0..15
    const int dir = db >> 3;
    const int b   = db & 7;

    const float4* __restrict__ Apack = packed + (dir ? (NB * NPTS + b * NPTS) : (b * NPTS));
    const float4* __restrict__ Bpack = packed + (dir ? (b * NPTS) : (NB * NPTS + b * NPTS));

    const int tid = threadIdx.x;
    const int a0i = aCh * APB + tid;
    const int a1i = a0i + THR;
    const float4 A0 = Apack[a0i];
    const float4 A1 = Apack[a1i];

    const float4* __restrict__ Bc = Bpack + bCh * BCHPTS;

    float m00 = 3e38f, m01 = 3e38f, m02 = 3e38f, m03 = 3e38f;
    float m10 = 3e38f, m11 = 3e38f, m12 = 3e38f, m13 = 3e38f;

    for (int j = 0; j < BCHPTS; j += 4) {
        // wave-uniform addresses -> scalar (SMEM) loads, free broadcast
        float4 q0 = Bc[j + 0];
        float4 q1 = Bc[j + 1];
        float4 q2 = Bc[j + 2];
        float4 q3 = Bc[j + 3];

        float d00 = fmaf(-2.f, fmaf(A0.x, q0.x, fmaf(A0.y, q0.y, A0.z * q0.z)), A0.w + q0.w);
        float d01 = fmaf(-2.f, fmaf(A0.x, q1.x, fmaf(A0.y, q1.y, A0.z * q1.z)), A0.w + q1.w);
        float d02 = fmaf(-2.f, fmaf(A0.x, q2.x, fmaf(A0.y, q2.y, A0.z * q2.z)), A0.w + q2.w);
        float d03 = fmaf(-2.f, fmaf(A0.x, q3.x, fmaf(A0.y, q3.y, A0.z * q3.z)), A0.w + q3.w);
        float d10 = fmaf(-2.f, fmaf(A1.x, q0.x, fmaf(A1.y, q0.y, A1.z * q0.z)), A1.w + q0.w);
        float d11 = fmaf(-2.f, fmaf(A1.x, q1.x, fmaf(A1.y, q1.y, A1.z * q1.z)), A1.w + q1.w);
        float d12 = fmaf(-2.f, fmaf(A1.x, q2.x, fmaf(A1.y, q2.y, A1.z * q2.z)), A1.w + q2.w);
        float d13 = fmaf(-2.f, fmaf(A1.x, q3.x, fmaf(A1.y, q3.y, A1.z * q3.z)), A1.w + q3.w);

        m00 = fminf(m00, d00); m01 = fminf(m01, d01);
        m02 = fminf(m02, d02); m03 = fminf(m03, d03);
        m10 = fminf(m10, d10); m11 = fminf(m11, d11);
        m12 = fminf(m12, d12); m13 = fminf(m13, d13);
    }
    float m0 = fminf(fminf(m00, m01), fminf(m02, m03));
    float m1 = fminf(fminf(m10, m11), fminf(m12, m13));

    // all distances positive -> int-min == float-min; sentinel 0x7F7F7F7F
    const int base = db * NPTS;
    atomicMin(&mins[base + a0i], __float_as_int(m0));
    atomicMin(&mins[base + a1i], __float_as_int(m1));
}

// ---------------- pass 2: sum of mins ----------------
__global__ __launch_bounds__(256) void reduce_kernel(
    const int* __restrict__ mins, float* __restrict__ out)
{
    const int nthreads = 64 * 256;
    int tid = blockIdx.x * 256 + threadIdx.x;
    float s = 0.f;
    for (int k = tid; k < 2 * NB * NPTS; k += nthreads)
        s += __int_as_float(mins[k]);

    #pragma unroll
    for (int off = 32; off > 0; off >>= 1)
        s += __shfl_down(s, off);

    __shared__ float red[4];
    const int lane = threadIdx.x & 63, wave = threadIdx.x >> 6;
    if (lane == 0) red[wave] = s;
    __syncthreads();
    if (threadIdx.x == 0) {
        float t = red[0] + red[1] + red[2] + red[3];
        atomicAdd(out, t * (0.005f / 32768.f));
    }
}

extern "C" void kernel_launch(void* const* d_in, const int* in_sizes, int n_in,
                              void* d_out, int out_size, void* d_ws, size_t ws_size,
                              hipStream_t stream) {
    const float* x = (const float*)d_in[0];
    const float* y = (const float*)d_in[1];
    float* out = (float*)d_out;

    float4* packed = (float4*)d_ws;                                  // 1 MB
    int*    mins   = (int*)((char*)d_ws + (size_t)2 * NB * NPTS * 16); // 256 KB

    // sentinel: 0x7F7F7F7F == 3.39e38f as float, > any distance
    hipMemsetAsync(mins, 0x7F, (size_t)2 * NB * NPTS * 4, stream);
    hipMemsetAsync(out, 0, sizeof(float), stream);

    prep_kernel<<<dim3(2 * NB * NPTS / 256), dim3(256), 0, stream>>>(x, y, packed);
    chamfer_main<<<dim3(2 * NB * ACH * BCH), dim3(THR), 0, stream>>>(packed, mins);
    reduce_kernel<<<dim3(64), dim3(256), 0, stream>>>(mins, out);
}

// Round 3
// 94.898 us; speedup vs baseline: 1.3831x; 1.1194x over previous
//
#include <hip/hip_runtime.h>

#define NPTS 4096
#define NB   8
#define CA   128                 // A points per block (64 lanes x 2)
#define WPB  8                   // waves per block (block = 512 threads)
#define BW   (NPTS / WPB)        // 512 B points per wave
#define UNR  8                   // B points per inner iteration

// ---------------- pass 0: pack (p0,p1,p2, h=-0.5*|p|^2), zero out ----------
__global__ __launch_bounds__(256) void prep_kernel(
    const float* __restrict__ x, const float* __restrict__ y,
    float4* __restrict__ packed, float* __restrict__ out)
{
    int i = blockIdx.x * 256 + threadIdx.x;          // 0..65535
    const float* src = (i < NB * NPTS) ? x : y;
    int j = (i < NB * NPTS) ? i : i - NB * NPTS;
    float p0 = src[3 * j + 0];
    float p1 = src[3 * j + 1];
    float p2 = src[3 * j + 2];
    packed[i] = make_float4(p0, p1, p2,
                            -0.5f * (p0 * p0 + p1 * p1 + p2 * p2));
    if (i == 0) *out = 0.f;
}

// ---------------- main: fused min + reduce ----------------
// grid = 2 dirs * 8 batches * 32 A-chunks = 512 blocks of 512 threads.
// Each wave: 128 A points (2/lane) vs its 512-pt B slice; LDS max-combine.
// min_j d = -2 * (max_j s + h_a), s = dot(a,b) + h_b
__global__ __launch_bounds__(512, 4) void chamfer_main(
    const float4* __restrict__ packed,
    float* __restrict__ out)
{
    __shared__ float sm[WPB * CA];   // 4 KB
    __shared__ float red[WPB];

    const int bid = blockIdx.x;
    const int aCh = bid & 31;
    const int db  = bid >> 5;        // dir*8 + batch
    const int b   = db & 7;
    const int dir = db >> 3;

    const float4* __restrict__ Apack =
        packed + (dir ? (NB * NPTS + b * NPTS) : (b * NPTS));
    const float4* __restrict__ Bpack =
        packed + (dir ? (b * NPTS) : (NB * NPTS + b * NPTS));

    const int tid  = threadIdx.x;
    const int lane = tid & 63;
    const int wv   = tid >> 6;

    const int a0i = aCh * CA + lane;
    const float4 A0 = Apack[a0i];
    const float4 A1 = Apack[a0i + 64];

    // wave-uniform B base -> SGPR (free broadcast, no per-lane addressing)
    const int boff = __builtin_amdgcn_readfirstlane(wv * BW);
    const float4* __restrict__ Bw = Bpack + boff;

    float m0 = -3e38f, m1 = -3e38f;

    float4 c[UNR], n[UNR];
    #pragma unroll
    for (int k = 0; k < UNR; ++k) c[k] = Bw[k];

    for (int j = UNR; j <= BW; j += UNR) {
        if (j < BW) {
            #pragma unroll
            for (int k = 0; k < UNR; ++k) n[k] = Bw[j + k];
        }
        #pragma unroll
        for (int k = 0; k < UNR; k += 2) {
            float4 q0 = c[k], q1 = c[k + 1];
            float s00 = fmaf(A0.x, q0.x, fmaf(A0.y, q0.y, fmaf(A0.z, q0.z, q0.w)));
            float s01 = fmaf(A0.x, q1.x, fmaf(A0.y, q1.y, fmaf(A0.z, q1.z, q1.w)));
            m0 = fmaxf(fmaxf(s00, s01), m0);            // v_max3_f32
            float s10 = fmaf(A1.x, q0.x, fmaf(A1.y, q0.y, fmaf(A1.z, q0.z, q0.w)));
            float s11 = fmaf(A1.x, q1.x, fmaf(A1.y, q1.y, fmaf(A1.z, q1.z, q1.w)));
            m1 = fmaxf(fmaxf(s10, s11), m1);
        }
        #pragma unroll
        for (int k = 0; k < UNR; ++k) c[k] = n[k];
    }

    sm[wv * CA + lane]      = m0;
    sm[wv * CA + lane + 64] = m1;
    __syncthreads();

    // combine the 8 waves' partial maxes, add h_a, sum
    float partial = 0.f;
    if (tid < CA) {
        float v = sm[tid];
        #pragma unroll
        for (int w = 1; w < WPB; ++w) v = fmaxf(v, sm[w * CA + tid]);
        partial = v + Apack[aCh * CA + tid].w;   // smax + h_a
    }

    #pragma unroll
    for (int off = 32; off > 0; off >>= 1)
        partial += __shfl_down(partial, off);

    if (lane == 0) red[wv] = partial;
    __syncthreads();

    if (tid == 0) {
        float t = red[0] + red[1] + red[2] + red[3]
                + red[4] + red[5] + red[6] + red[7];
        // loss contribution: sum of -2*(smax+h_a), scaled by 0.005/32768
        atomicAdd(out, t * (-2.0f * 0.005f / 32768.f));
    }
}

extern "C" void kernel_launch(void* const* d_in, const int* in_sizes, int n_in,
                              void* d_out, int out_size, void* d_ws, size_t ws_size,
                              hipStream_t stream) {
    const float* x = (const float*)d_in[0];
    const float* y = (const float*)d_in[1];
    float* out = (float*)d_out;

    float4* packed = (float4*)d_ws;   // 1 MB

    prep_kernel<<<dim3(2 * NB * NPTS / 256), dim3(256), 0, stream>>>(x, y, packed, out);
    chamfer_main<<<dim3(2 * NB * (NPTS / CA)), dim3(512), 0, stream>>>(packed, out);
}

// Round 4
// 83.410 us; speedup vs baseline: 1.5736x; 1.1377x over previous
//
#include <hip/hip_runtime.h>

#define NPTS  4096
#define NB    8
#define TOT   (2 * NB * NPTS)      // 65536 A points across both directions
#define THR   128                  // threads per block (2 waves)
#define APT   8                    // A points per thread
#define APB   (THR * APT)          // 1024 A points per block
#define AUNITS (TOT / APB)         // 64
#define BCH   16                   // B chunks per cloud
#define BCHP  (NPTS / BCH)         // 256 B points per chunk

// packed[0..32767] = x clouds, packed[32768..65535] = y clouds,
// each entry (p0,p1,p2, h = -0.5*|p|^2).
// min_j d = -2 * (max_j s + h_a),  s = dot(a,b) + h_b

// ---------------- pass 0: pack + init smax + zero out ----------------
__global__ __launch_bounds__(256) void prep_kernel(
    const float* __restrict__ x, const float* __restrict__ y,
    float4* __restrict__ packed, unsigned* __restrict__ smax,
    float* __restrict__ out)
{
    int i = blockIdx.x * 256 + threadIdx.x;          // 0..65535
    const float* src = (i < NB * NPTS) ? x : y;
    int j = (i < NB * NPTS) ? i : i - NB * NPTS;
    float p0 = src[3 * j + 0];
    float p1 = src[3 * j + 1];
    float p2 = src[3 * j + 2];
    packed[i] = make_float4(p0, p1, p2,
                            -0.5f * (p0 * p0 + p1 * p1 + p2 * p2));
    smax[i] = 0u;        // below any order-mapped finite float
    if (i == 0) *out = 0.f;
}

// ---------------- pass 1: partial max over a 256-pt B chunk ----------------
// grid = AUNITS * BCH = 1024 blocks of 128 threads.
__global__ __launch_bounds__(THR) void chamfer_main(
    const float4* __restrict__ packed,
    unsigned* __restrict__ smax)
{
    __shared__ float4 sB[BCHP];   // 4 KB

    const int bid   = blockIdx.x;
    const int bCh   = bid & (BCH - 1);
    const int aU    = bid >> 4;
    const int aBase = aU * APB;                  // global A index base
    const int dir   = aBase >> 15;               // 0: A=x, 1: A=y
    const int b     = (aBase >> 12) & 7;

    const float4* __restrict__ Bb =
        packed + (dir ? (b * NPTS) : (NB * NPTS + b * NPTS));
    const float4* __restrict__ Bc = Bb + bCh * BCHP;

    const int tid = threadIdx.x;

    // stage B chunk (coalesced dwordx4 -> ds_write_b128)
    for (int k = tid; k < BCHP; k += THR)
        sB[k] = Bc[k];

    // own A points (coalesced)
    float a0[APT], a1[APT], a2[APT], m[APT];
    #pragma unroll
    for (int k = 0; k < APT; ++k) {
        float4 A = packed[aBase + k * THR + tid];
        a0[k] = A.x; a1[k] = A.y; a2[k] = A.z;
        m[k] = -3e38f;
    }

    __syncthreads();

    // 28 VALU per ds_read_b128 -> LDS pipe fully hidden under VALU
    #pragma unroll 2
    for (int j = 0; j < BCHP; j += 2) {
        float4 qa = sB[j];
        float4 qb = sB[j + 1];
        #pragma unroll
        for (int k = 0; k < APT; ++k) {
            float sa = fmaf(a0[k], qa.x, fmaf(a1[k], qa.y, fmaf(a2[k], qa.z, qa.w)));
            float sb = fmaf(a0[k], qb.x, fmaf(a1[k], qb.y, fmaf(a2[k], qb.z, qb.w)));
            m[k] = fmaxf(fmaxf(sa, sb), m[k]);   // v_max3_f32
        }
    }

    // order-preserving float->uint map (works for negatives), atomic combine
    #pragma unroll
    for (int k = 0; k < APT; ++k) {
        unsigned bits = __float_as_uint(m[k]);
        unsigned u = (bits & 0x80000000u) ? ~bits : (bits | 0x80000000u);
        atomicMax(&smax[aBase + k * THR + tid], u);
    }
}

// ---------------- pass 2: unmap, add h_a, sum ----------------
__global__ __launch_bounds__(256) void reduce_kernel(
    const unsigned* __restrict__ smax,
    const float4* __restrict__ packed,
    float* __restrict__ out)
{
    const int stride = 64 * 256;
    int tid = blockIdx.x * 256 + threadIdx.x;
    float s = 0.f;
    for (int k = tid; k < TOT; k += stride) {
        unsigned u = smax[k];
        unsigned bits = (u & 0x80000000u) ? (u & 0x7FFFFFFFu) : ~u;
        s += __uint_as_float(bits) + packed[k].w;    // smax + h_a
    }

    #pragma unroll
    for (int off = 32; off > 0; off >>= 1)
        s += __shfl_down(s, off);

    __shared__ float red[4];
    const int lane = threadIdx.x & 63, wave = threadIdx.x >> 6;
    if (lane == 0) red[wave] = s;
    __syncthreads();
    if (threadIdx.x == 0) {
        float t = red[0] + red[1] + red[2] + red[3];
        // loss contribution: -2*(smax+h_a) summed, * 0.005 / 32768
        atomicAdd(out, t * (-2.0f * 0.005f / 32768.f));
    }
}

extern "C" void kernel_launch(void* const* d_in, const int* in_sizes, int n_in,
                              void* d_out, int out_size, void* d_ws, size_t ws_size,
                              hipStream_t stream) {
    const float* x = (const float*)d_in[0];
    const float* y = (const float*)d_in[1];
    float* out = (float*)d_out;

    float4*   packed = (float4*)d_ws;                               // 1 MB
    unsigned* smax   = (unsigned*)((char*)d_ws + (size_t)TOT * 16); // 256 KB

    prep_kernel<<<dim3(TOT / 256), dim3(256), 0, stream>>>(x, y, packed, smax, out);
    chamfer_main<<<dim3(AUNITS * BCH), dim3(THR), 0, stream>>>(packed, smax);
    reduce_kernel<<<dim3(64), dim3(256), 0, stream>>>(smax, packed, out);
}